// Round 2
// baseline (869.106 us; speedup 1.0000x reference)
//
#include <hip/hip_runtime.h>
#include <cstdint>

#define LEAKY 0.2f
#define LN_EPS 1e-5f

// ---------------------------------------------------------------------------
// CSR build: histogram of dst, exclusive scan, scatter src into col[]
// ---------------------------------------------------------------------------
__global__ void hist_kernel(const int* __restrict__ ei, int er, int etot,
                            int* __restrict__ deg) {
    int e = blockIdx.x * blockDim.x + threadIdx.x;
    if (e >= etot) return;
    int dst = (e < er) ? ei[er + e] : (e - er);   // self-loops appended
    atomicAdd(&deg[dst], 1);
}

__global__ __launch_bounds__(1024) void scan_kernel(const int* __restrict__ deg,
                                                    int* __restrict__ offs,
                                                    int* __restrict__ woff, int n) {
    __shared__ int wsum[16];
    __shared__ int wpre[16];
    __shared__ int carry_s;
    const int t = threadIdx.x, lane = t & 63, wv = t >> 6;
    if (t == 0) carry_s = 0;
    __syncthreads();
    for (int base = 0; base < n; base += 1024) {
        int i = base + t;
        int v = (i < n) ? deg[i] : 0;
        int x = v;
#pragma unroll
        for (int off = 1; off < 64; off <<= 1) {
            int y = __shfl_up(x, off, 64);
            if (lane >= off) x += y;
        }
        if (lane == 63) wsum[wv] = x;
        __syncthreads();
        if (wv == 0) {
            int s = (lane < 16) ? wsum[lane] : 0;
#pragma unroll
            for (int off = 1; off < 16; off <<= 1) {
                int y = __shfl_up(s, off, 64);
                if (lane >= off) s += y;
            }
            if (lane < 16) wpre[lane] = s;
        }
        __syncthreads();
        int carry = carry_s;
        int incl = x + (wv > 0 ? wpre[wv - 1] : 0);
        int excl = carry + incl - v;
        if (i < n) { offs[i] = excl; woff[i] = excl; }
        __syncthreads();
        if (t == 1023) carry_s = carry + incl;
        __syncthreads();
    }
    if (t == 0) offs[n] = carry_s;
}

__global__ void fill_kernel(const int* __restrict__ ei, int er, int etot,
                            int* __restrict__ woff, int* __restrict__ colv) {
    int e = blockIdx.x * blockDim.x + threadIdx.x;
    if (e >= etot) return;
    int src, dst;
    if (e < er) { src = ei[e]; dst = ei[er + e]; }
    else        { src = dst = e - er; }
    int pos = atomicAdd(&woff[dst], 1);
    colv[pos] = src;
}

// ---------------------------------------------------------------------------
// Dual GEMM: Ol = X@Wl, Or = X@Wr  (128-row tile, W + X tile in LDS = 128 KiB)
// ---------------------------------------------------------------------------
__global__ __launch_bounds__(256, 1) void gemm_dual(
    const float* __restrict__ X,
    const float* __restrict__ Wl, const float* __restrict__ Wr,
    float* __restrict__ Ol, float* __restrict__ Or, int nrows) {
    const float* __restrict__ W = blockIdx.y ? Wr : Wl;
    float* __restrict__ O = blockIdx.y ? Or : Ol;
    __shared__ float xs[128][128];   // 64 KiB
    __shared__ float ws[128][128];   // 64 KiB
    const int t = threadIdx.x;
    {   // stage W: 4096 float4, 16 per thread
        const float4* Wv = (const float4*)W;
        float4* wsv = (float4*)&ws[0][0];
#pragma unroll
        for (int i = 0; i < 16; ++i) wsv[i * 256 + t] = Wv[i * 256 + t];
    }
    const int r0 = blockIdx.x * 128;
    {   // stage X tile
#pragma unroll
        for (int i = 0; i < 16; ++i) {
            int idx = i * 256 + t;          // float4 index in 128x32 grid
            int r = idx >> 5, c = idx & 31;
            float4 v = {0.f, 0.f, 0.f, 0.f};
            if (r0 + r < nrows) v = ((const float4*)X)[(size_t)(r0 + r) * 32 + c];
            *(float4*)&xs[r][c * 4] = v;
        }
    }
    __syncthreads();
    const int cg = t & 15;   // 16 col groups: cols {4cg..4cg+3} and {64+4cg..}
    const int rg = t >> 4;   // 16 row groups x 8 rows
    float acc[8][8];
#pragma unroll
    for (int i = 0; i < 8; ++i)
#pragma unroll
        for (int j = 0; j < 8; ++j) acc[i][j] = 0.f;

    for (int k = 0; k < 128; k += 4) {
        float4 xv[8];
#pragma unroll
        for (int i = 0; i < 8; ++i) xv[i] = *(const float4*)&xs[rg * 8 + i][k];
#pragma unroll
        for (int kk = 0; kk < 4; ++kk) {
            float4 w0 = *(const float4*)&ws[k + kk][cg * 4];
            float4 w1 = *(const float4*)&ws[k + kk][64 + cg * 4];
#pragma unroll
            for (int i = 0; i < 8; ++i) {
                float xx = ((const float*)&xv[i])[kk];
                acc[i][0] += xx * w0.x; acc[i][1] += xx * w0.y;
                acc[i][2] += xx * w0.z; acc[i][3] += xx * w0.w;
                acc[i][4] += xx * w1.x; acc[i][5] += xx * w1.y;
                acc[i][6] += xx * w1.z; acc[i][7] += xx * w1.w;
            }
        }
    }
#pragma unroll
    for (int i = 0; i < 8; ++i) {
        int r = r0 + rg * 8 + i;
        if (r < nrows) {
            float4 o0 = {acc[i][0], acc[i][1], acc[i][2], acc[i][3]};
            float4 o1 = {acc[i][4], acc[i][5], acc[i][6], acc[i][7]};
            *(float4*)&O[(size_t)r * 128 + cg * 4] = o0;
            *(float4*)&O[(size_t)r * 128 + 64 + cg * 4] = o1;
        }
    }
}

// ---------------------------------------------------------------------------
// Fused GATv2 aggregation + bias + ELU + residual + LayerNorm.
// One wave (64 lanes) per destination node; lane owns features 2l, 2l+1.
// ---------------------------------------------------------------------------
__global__ __launch_bounds__(256) void gat_agg(
    const float* __restrict__ xl, const float* __restrict__ xr,
    const int* __restrict__ offs, const int* __restrict__ colv,
    const float* __restrict__ att,   // [8][16] flat
    const float* __restrict__ bias, const float* __restrict__ gamma,
    const float* __restrict__ beta, const float* __restrict__ resid,
    float* __restrict__ out, int nnode) {
    int gid = blockIdx.x * (blockDim.x >> 6) + (threadIdx.x >> 6);
    if (gid >= nnode) return;
    const int lane = threadIdx.x & 63;
    const float2 att2 = ((const float2*)att)[lane];
    const float2 xr2 = ((const float2*)xr)[(size_t)gid * 64 + lane];
    float den = 0.f, acc0 = 0.f, acc1 = 0.f;
    int e = offs[gid];
    const int e1 = offs[gid + 1];
    for (; e + 2 <= e1; e += 2) {   // 2-edge unroll for memory-level parallelism
        int s0 = colv[e], s1 = colv[e + 1];
        float2 a0 = ((const float2*)xl)[(size_t)s0 * 64 + lane];
        float2 a1 = ((const float2*)xl)[(size_t)s1 * 64 + lane];
        float m0x = a0.x + xr2.x, m0y = a0.y + xr2.y;
        m0x = m0x > 0.f ? m0x : LEAKY * m0x;
        m0y = m0y > 0.f ? m0y : LEAKY * m0y;
        float p0 = m0x * att2.x + m0y * att2.y;
        float m1x = a1.x + xr2.x, m1y = a1.y + xr2.y;
        m1x = m1x > 0.f ? m1x : LEAKY * m1x;
        m1y = m1y > 0.f ? m1y : LEAKY * m1y;
        float p1 = m1x * att2.x + m1y * att2.y;
        p0 += __shfl_xor(p0, 1); p0 += __shfl_xor(p0, 2); p0 += __shfl_xor(p0, 4);
        p1 += __shfl_xor(p1, 1); p1 += __shfl_xor(p1, 2); p1 += __shfl_xor(p1, 4);
        float ex0 = expf(p0), ex1 = expf(p1);
        den += ex0 + ex1;
        acc0 += a0.x * ex0 + a1.x * ex1;
        acc1 += a0.y * ex0 + a1.y * ex1;
    }
    if (e < e1) {
        int s0 = colv[e];
        float2 a0 = ((const float2*)xl)[(size_t)s0 * 64 + lane];
        float m0x = a0.x + xr2.x, m0y = a0.y + xr2.y;
        m0x = m0x > 0.f ? m0x : LEAKY * m0x;
        m0y = m0y > 0.f ? m0y : LEAKY * m0y;
        float p0 = m0x * att2.x + m0y * att2.y;
        p0 += __shfl_xor(p0, 1); p0 += __shfl_xor(p0, 2); p0 += __shfl_xor(p0, 4);
        float ex0 = expf(p0);
        den += ex0;
        acc0 += a0.x * ex0;
        acc1 += a0.y * ex0;
    }
    float inv_den = 1.f / den;           // den identical across a head's 8 lanes
    const float2 b2 = ((const float2*)bias)[lane];
    float v0 = acc0 * inv_den + b2.x;
    float v1 = acc1 * inv_den + b2.y;
    v0 = v0 > 0.f ? v0 : expm1f(v0);     // ELU (alpha=1)
    v1 = v1 > 0.f ? v1 : expm1f(v1);
    const float2 r2 = ((const float2*)resid)[(size_t)gid * 64 + lane];
    float t0 = v0 + r2.x, t1 = v1 + r2.y;
    float s = t0 + t1, ss = t0 * t0 + t1 * t1;
#pragma unroll
    for (int m = 1; m < 64; m <<= 1) {
        s += __shfl_xor(s, m);
        ss += __shfl_xor(ss, m);
    }
    const float mu = s * 0.0078125f;               // /128
    const float var = ss * 0.0078125f - mu * mu;
    const float iv = rsqrtf(var + LN_EPS);
    const float2 g2 = ((const float2*)gamma)[lane];
    const float2 be2 = ((const float2*)beta)[lane];
    float2 o;
    o.x = (t0 - mu) * iv * g2.x + be2.x;
    o.y = (t1 - mu) * iv * g2.y + be2.y;
    ((float2*)out)[(size_t)gid * 64 + lane] = o;
}

// ---------------------------------------------------------------------------
extern "C" void kernel_launch(void* const* d_in, const int* in_sizes, int n_in,
                              void* d_out, int out_size, void* d_ws, size_t ws_size,
                              hipStream_t stream) {
    const float* x   = (const float*)d_in[0];
    const int*   ei  = (const int*)d_in[1];
    const float* Wl0 = (const float*)d_in[2];
    const float* Wr0 = (const float*)d_in[3];
    const float* at0 = (const float*)d_in[4];
    const float* b0  = (const float*)d_in[5];
    const float* g0  = (const float*)d_in[6];
    const float* be0 = (const float*)d_in[7];
    const float* Wl1 = (const float*)d_in[8];
    const float* Wr1 = (const float*)d_in[9];
    const float* at1 = (const float*)d_in[10];
    const float* b1  = (const float*)d_in[11];
    const float* g1  = (const float*)d_in[12];
    const float* be1 = (const float*)d_in[13];

    const int NF = in_sizes[0];        // N*128
    const int n  = NF / 128;           // nodes
    const int er = in_sizes[1] / 2;    // raw edges
    const int etot = er + n;           // + self-loops

    float* A   = (float*)d_ws;         // xl  (N*128)
    float* B   = A + (size_t)NF;       // xr  (N*128)
    int* deg   = (int*)(B + (size_t)NF);
    int* woff  = deg + n;
    int* offs  = woff + n;
    int* colv  = offs + (n + 1);
    float* C   = (float*)d_out;        // layer-1 output / residual / final out

    // ---- CSR build (shared by both layers) ----
    hipMemsetAsync(deg, 0, (size_t)n * sizeof(int), stream);
    hist_kernel<<<(etot + 255) / 256, 256, 0, stream>>>(ei, er, etot, deg);
    scan_kernel<<<1, 1024, 0, stream>>>(deg, offs, woff, n);
    fill_kernel<<<(etot + 255) / 256, 256, 0, stream>>>(ei, er, etot, woff, colv);

    dim3 ggrid((n + 127) / 128, 2);

    // ---- layer 1 ----
    gemm_dual<<<ggrid, 256, 0, stream>>>(x, Wl0, Wr0, A, B, n);
    gat_agg<<<(n + 3) / 4, 256, 0, stream>>>(A, B, offs, colv, at0, b0, g0, be0,
                                             x, C, n);
    // ---- layer 2 (in-place finalize on d_out is safe: elementwise R-then-W) ----
    gemm_dual<<<ggrid, 256, 0, stream>>>(C, Wl1, Wr1, A, B, n);
    gat_agg<<<(n + 3) / 4, 256, 0, stream>>>(A, B, offs, colv, at1, b1, g1, be1,
                                             C, C, n);
}

// Round 3
// 728.017 us; speedup vs baseline: 1.1938x; 1.1938x over previous
//
#include <hip/hip_runtime.h>
#include <cstdint>

#define LEAKY 0.2f
#define LN_EPS 1e-5f

typedef __attribute__((ext_vector_type(8))) short short8;   // 8 x bf16 (4 VGPR)
typedef __attribute__((ext_vector_type(4))) float f32x4;    // MFMA accum

__device__ __forceinline__ ushort bf16_rne(float x) {
    unsigned u = __float_as_uint(x);
    unsigned r = (u + 0x7fffu + ((u >> 16) & 1u)) >> 16;
    return (ushort)r;
}
__device__ __forceinline__ float bf16_to_f(ushort h) {
    return __uint_as_float(((unsigned)h) << 16);
}

// ---------------------------------------------------------------------------
// CSR build: histogram of dst, exclusive scan, scatter src into col[]
// ---------------------------------------------------------------------------
__global__ void hist_kernel(const int* __restrict__ ei, int er, int etot,
                            int* __restrict__ deg) {
    int e = blockIdx.x * blockDim.x + threadIdx.x;
    if (e >= etot) return;
    int dst = (e < er) ? ei[er + e] : (e - er);   // self-loops appended
    atomicAdd(&deg[dst], 1);
}

__global__ __launch_bounds__(1024) void scan_kernel(const int* __restrict__ deg,
                                                    int* __restrict__ offs,
                                                    int* __restrict__ woff, int n) {
    __shared__ int wsum[16];
    __shared__ int wpre[16];
    __shared__ int carry_s;
    const int t = threadIdx.x, lane = t & 63, wv = t >> 6;
    if (t == 0) carry_s = 0;
    __syncthreads();
    for (int base = 0; base < n; base += 1024) {
        int i = base + t;
        int v = (i < n) ? deg[i] : 0;
        int x = v;
#pragma unroll
        for (int off = 1; off < 64; off <<= 1) {
            int y = __shfl_up(x, off, 64);
            if (lane >= off) x += y;
        }
        if (lane == 63) wsum[wv] = x;
        __syncthreads();
        if (wv == 0) {
            int s = (lane < 16) ? wsum[lane] : 0;
#pragma unroll
            for (int off = 1; off < 16; off <<= 1) {
                int y = __shfl_up(s, off, 64);
                if (lane >= off) s += y;
            }
            if (lane < 16) wpre[lane] = s;
        }
        __syncthreads();
        int carry = carry_s;
        int incl = x + (wv > 0 ? wpre[wv - 1] : 0);
        int excl = carry + incl - v;
        if (i < n) { offs[i] = excl; woff[i] = excl; }
        __syncthreads();
        if (t == 1023) carry_s = carry + incl;
        __syncthreads();
    }
    if (t == 0) offs[n] = carry_s;
}

__global__ void fill_kernel(const int* __restrict__ ei, int er, int etot,
                            int* __restrict__ woff, int* __restrict__ colv) {
    int e = blockIdx.x * blockDim.x + threadIdx.x;
    if (e >= etot) return;
    int src, dst;
    if (e < er) { src = ei[e]; dst = ei[er + e]; }
    else        { src = dst = e - er; }
    int pos = atomicAdd(&woff[dst], 1);
    colv[pos] = src;
}

// ---------------------------------------------------------------------------
// W transpose + split-bf16 convert: Wt[col][k], col 0..127 = Wl, 128..255 = Wr
// ---------------------------------------------------------------------------
__global__ void cvt_w(const float* __restrict__ Wl, const float* __restrict__ Wr,
                      ushort* __restrict__ Whi, ushort* __restrict__ Wlo) {
    int idx = blockIdx.x * 256 + threadIdx.x;   // col*128 + k, 32768 total
    int col = idx >> 7, k = idx & 127;
    float v = (col < 128) ? Wl[(size_t)k * 128 + col]
                          : Wr[(size_t)k * 128 + (col - 128)];
    ushort h = bf16_rne(v);
    Whi[idx] = h;
    Wlo[idx] = bf16_rne(v - bf16_to_f(h));
}

// ---------------------------------------------------------------------------
// Dual GEMM via split-bf16 MFMA (hi*hi + hi*lo + lo*hi ~= fp32 precision).
// Block = 4 waves; wave w computes rows [64*bx,64*bx+64) x cols [64w,64w+64)
// of X @ [Wl|Wr]. A-frags: fp32 X loaded 32B/lane, converted in-register.
// B-frags: bf16 Wt (pre-transposed [256][128]) 16B/lane. No LDS.
// ---------------------------------------------------------------------------
__global__ __launch_bounds__(256) void gemm_mfma(
    const float* __restrict__ X,
    const ushort* __restrict__ Whi, const ushort* __restrict__ Wlo,
    float* __restrict__ Ol, float* __restrict__ Or, int nrows) {
    const int wave = threadIdx.x >> 6;
    const int lane = threadIdx.x & 63;
    const int lrow = lane & 15;
    const int lk = (lane >> 4) << 3;          // 0,8,16,24
    const int m0 = blockIdx.x * 64;
    const int n0 = wave * 64;

    f32x4 acc[4][4];
#pragma unroll
    for (int mt = 0; mt < 4; ++mt)
#pragma unroll
        for (int nt = 0; nt < 4; ++nt) acc[mt][nt] = (f32x4){0.f, 0.f, 0.f, 0.f};

#pragma unroll
    for (int ks = 0; ks < 4; ++ks) {
        const int kb = ks * 32 + lk;
        short8 ahi[4], alo[4];
#pragma unroll
        for (int mt = 0; mt < 4; ++mt) {
            const int row = m0 + mt * 16 + lrow;
            float4 v0 = {0.f, 0.f, 0.f, 0.f}, v1 = {0.f, 0.f, 0.f, 0.f};
            if (row < nrows) {
                const float* p = X + (size_t)row * 128 + kb;
                v0 = *(const float4*)p;
                v1 = *(const float4*)(p + 4);
            }
            float e[8];
            e[0] = v0.x; e[1] = v0.y; e[2] = v0.z; e[3] = v0.w;
            e[4] = v1.x; e[5] = v1.y; e[6] = v1.z; e[7] = v1.w;
#pragma unroll
            for (int j = 0; j < 8; ++j) {
                ushort h = bf16_rne(e[j]);
                ahi[mt][j] = (short)h;
                alo[mt][j] = (short)bf16_rne(e[j] - bf16_to_f(h));
            }
        }
#pragma unroll
        for (int nt = 0; nt < 4; ++nt) {
            const int col = n0 + nt * 16 + lrow;
            short8 bhi = *(const short8*)&Whi[(size_t)col * 128 + kb];
            short8 blo = *(const short8*)&Wlo[(size_t)col * 128 + kb];
#pragma unroll
            for (int mt = 0; mt < 4; ++mt) {
                acc[mt][nt] = __builtin_amdgcn_mfma_f32_16x16x32_bf16(
                    alo[mt], bhi, acc[mt][nt], 0, 0, 0);
                acc[mt][nt] = __builtin_amdgcn_mfma_f32_16x16x32_bf16(
                    ahi[mt], blo, acc[mt][nt], 0, 0, 0);
                acc[mt][nt] = __builtin_amdgcn_mfma_f32_16x16x32_bf16(
                    ahi[mt], bhi, acc[mt][nt], 0, 0, 0);
            }
        }
    }
    // Epilogue. C/D frag: col = lane&15, row = (lane>>4)*4 + i  [m89 layout].
    // wave 0,1 -> cols 0..127 (Ol); wave 2,3 -> cols 128..255 (Or).
    float* __restrict__ O = (wave < 2) ? Ol : Or;
    const int cbase = (n0 & 127);
    const int crow0 = (lane >> 4) * 4;
#pragma unroll
    for (int mt = 0; mt < 4; ++mt) {
#pragma unroll
        for (int i = 0; i < 4; ++i) {
            const int row = m0 + mt * 16 + crow0 + i;
            if (row >= nrows) continue;
#pragma unroll
            for (int nt = 0; nt < 4; ++nt) {
                const int col = cbase + nt * 16 + lrow;
                O[(size_t)row * 128 + col] = acc[mt][nt][i];
            }
        }
    }
}

// ---------------------------------------------------------------------------
// Fused GATv2 aggregation + bias + ELU + residual + LayerNorm.
// One wave (64 lanes) per destination node; lane owns features 2l, 2l+1.
// ---------------------------------------------------------------------------
__global__ __launch_bounds__(256) void gat_agg(
    const float* __restrict__ xl, const float* __restrict__ xr,
    const int* __restrict__ offs, const int* __restrict__ colv,
    const float* __restrict__ att,   // [8][16] flat
    const float* __restrict__ bias, const float* __restrict__ gamma,
    const float* __restrict__ beta, const float* __restrict__ resid,
    float* __restrict__ out, int nnode) {
    int gid = blockIdx.x * (blockDim.x >> 6) + (threadIdx.x >> 6);
    if (gid >= nnode) return;
    const int lane = threadIdx.x & 63;
    const float2* __restrict__ xlb = (const float2*)xl + lane;
    const float2 att2 = ((const float2*)att)[lane];
    const float2 xr2 = ((const float2*)xr)[(size_t)gid * 64 + lane];
    float den = 0.f, acc0 = 0.f, acc1 = 0.f;
    int e = offs[gid];
    const int e1 = offs[gid + 1];
    for (; e + 2 <= e1; e += 2) {   // 2-edge unroll for memory-level parallelism
        int s0 = colv[e], s1 = colv[e + 1];
        float2 a0 = xlb[(size_t)s0 * 64];
        float2 a1 = xlb[(size_t)s1 * 64];
        float m0x = a0.x + xr2.x, m0y = a0.y + xr2.y;
        m0x = fmaxf(m0x, LEAKY * m0x);          // leaky (slope<1): max(x, 0.2x)
        m0y = fmaxf(m0y, LEAKY * m0y);
        float p0 = m0x * att2.x + m0y * att2.y;
        float m1x = a1.x + xr2.x, m1y = a1.y + xr2.y;
        m1x = fmaxf(m1x, LEAKY * m1x);
        m1y = fmaxf(m1y, LEAKY * m1y);
        float p1 = m1x * att2.x + m1y * att2.y;
        p0 += __shfl_xor(p0, 1); p0 += __shfl_xor(p0, 2); p0 += __shfl_xor(p0, 4);
        p1 += __shfl_xor(p1, 1); p1 += __shfl_xor(p1, 2); p1 += __shfl_xor(p1, 4);
        float ex0 = __expf(p0), ex1 = __expf(p1);
        den += ex0 + ex1;
        acc0 += a0.x * ex0 + a1.x * ex1;
        acc1 += a0.y * ex0 + a1.y * ex1;
    }
    if (e < e1) {
        int s0 = colv[e];
        float2 a0 = xlb[(size_t)s0 * 64];
        float m0x = a0.x + xr2.x, m0y = a0.y + xr2.y;
        m0x = fmaxf(m0x, LEAKY * m0x);
        m0y = fmaxf(m0y, LEAKY * m0y);
        float p0 = m0x * att2.x + m0y * att2.y;
        p0 += __shfl_xor(p0, 1); p0 += __shfl_xor(p0, 2); p0 += __shfl_xor(p0, 4);
        float ex0 = __expf(p0);
        den += ex0;
        acc0 += a0.x * ex0;
        acc1 += a0.y * ex0;
    }
    float inv_den = 1.f / den;           // den identical across a head's 8 lanes
    const float2 b2 = ((const float2*)bias)[lane];
    float v0 = acc0 * inv_den + b2.x;
    float v1 = acc1 * inv_den + b2.y;
    v0 = v0 > 0.f ? v0 : expm1f(v0);     // ELU (alpha=1)
    v1 = v1 > 0.f ? v1 : expm1f(v1);
    const float2 r2 = ((const float2*)resid)[(size_t)gid * 64 + lane];
    float t0 = v0 + r2.x, t1 = v1 + r2.y;
    float s = t0 + t1, ss = t0 * t0 + t1 * t1;
#pragma unroll
    for (int m = 1; m < 64; m <<= 1) {
        s += __shfl_xor(s, m);
        ss += __shfl_xor(ss, m);
    }
    const float mu = s * 0.0078125f;               // /128
    const float var = ss * 0.0078125f - mu * mu;
    const float iv = rsqrtf(var + LN_EPS);
    const float2 g2 = ((const float2*)gamma)[lane];
    const float2 be2 = ((const float2*)beta)[lane];
    float2 o;
    o.x = (t0 - mu) * iv * g2.x + be2.x;
    o.y = (t1 - mu) * iv * g2.y + be2.y;
    ((float2*)out)[(size_t)gid * 64 + lane] = o;
}

// ---------------------------------------------------------------------------
extern "C" void kernel_launch(void* const* d_in, const int* in_sizes, int n_in,
                              void* d_out, int out_size, void* d_ws, size_t ws_size,
                              hipStream_t stream) {
    const float* x   = (const float*)d_in[0];
    const int*   ei  = (const int*)d_in[1];
    const float* Wl0 = (const float*)d_in[2];
    const float* Wr0 = (const float*)d_in[3];
    const float* at0 = (const float*)d_in[4];
    const float* b0  = (const float*)d_in[5];
    const float* g0  = (const float*)d_in[6];
    const float* be0 = (const float*)d_in[7];
    const float* Wl1 = (const float*)d_in[8];
    const float* Wr1 = (const float*)d_in[9];
    const float* at1 = (const float*)d_in[10];
    const float* b1  = (const float*)d_in[11];
    const float* g1  = (const float*)d_in[12];
    const float* be1 = (const float*)d_in[13];

    const int NF = in_sizes[0];        // N*128
    const int n  = NF / 128;           // nodes
    const int er = in_sizes[1] / 2;    // raw edges
    const int etot = er + n;           // + self-loops

    float* A    = (float*)d_ws;        // xl  (N*128)
    float* B    = A + (size_t)NF;      // xr  (N*128)
    ushort* Whi = (ushort*)(B + (size_t)NF);   // 256*128 bf16 hi
    ushort* Wlo = Whi + 32768;                 // 256*128 bf16 lo
    int* deg    = (int*)(Wlo + 32768);
    int* woff   = deg + n;
    int* offs   = woff + n;
    int* colv   = offs + (n + 1);
    float* C    = (float*)d_out;       // layer-1 output / residual / final out

    // ---- CSR build (shared by both layers) ----
    hipMemsetAsync(deg, 0, (size_t)n * sizeof(int), stream);
    hist_kernel<<<(etot + 255) / 256, 256, 0, stream>>>(ei, er, etot, deg);
    scan_kernel<<<1, 1024, 0, stream>>>(deg, offs, woff, n);
    fill_kernel<<<(etot + 255) / 256, 256, 0, stream>>>(ei, er, etot, woff, colv);

    const int gblk = (n + 63) / 64;

    // ---- layer 1 ----
    cvt_w<<<128, 256, 0, stream>>>(Wl0, Wr0, Whi, Wlo);
    gemm_mfma<<<gblk, 256, 0, stream>>>(x, Whi, Wlo, A, B, n);
    gat_agg<<<(n + 3) / 4, 256, 0, stream>>>(A, B, offs, colv, at0, b0, g0, be0,
                                             x, C, n);
    // ---- layer 2 (in-place finalize on d_out is safe: elementwise R-then-W) ----
    cvt_w<<<128, 256, 0, stream>>>(Wl1, Wr1, Whi, Wlo);
    gemm_mfma<<<gblk, 256, 0, stream>>>(C, Whi, Wlo, A, B, n);
    gat_agg<<<(n + 3) / 4, 256, 0, stream>>>(A, B, offs, colv, at1, b1, g1, be1,
                                             C, C, n);
}